// Round 1
// baseline (55.445 us; speedup 1.0000x reference)
//
#include <hip/hip_runtime.h>

// out[k] = sum_{n<100} sum_{d<4} x[d] * M[n][d][k]
// M flat: 1600 floats = 400 rows of float4; row r -> (n = r>>2, d = r&3).
// One wave does everything: problem is 6.4 KB total -> launch-overhead bound.
__global__ void __launch_bounds__(64)
big_fanout_kernel(const float* __restrict__ x,
                  const float* __restrict__ M,
                  float* __restrict__ out) {
    const int lane = threadIdx.x;  // 0..63, single wave

    // broadcast x (4 floats, L1-cached)
    const float x0 = x[0], x1 = x[1], x2 = x[2], x3 = x[3];

    float a0 = 0.f, a1 = 0.f, a2 = 0.f, a3 = 0.f;

    const float4* __restrict__ rows = (const float4*)M;
    // 400 rows, 64 lanes -> up to 7 iterations/lane, coalesced float4 loads
    for (int r = lane; r < 400; r += 64) {
        const float4 row = rows[r];
        const int d = r & 3;
        const float w = (d == 0) ? x0 : (d == 1) ? x1 : (d == 2) ? x2 : x3;
        a0 = fmaf(w, row.x, a0);
        a1 = fmaf(w, row.y, a1);
        a2 = fmaf(w, row.z, a2);
        a3 = fmaf(w, row.w, a3);
    }

    // 64-lane wave reduction (wavefront = 64 on CDNA)
    #pragma unroll
    for (int off = 32; off > 0; off >>= 1) {
        a0 += __shfl_down(a0, off);
        a1 += __shfl_down(a1, off);
        a2 += __shfl_down(a2, off);
        a3 += __shfl_down(a3, off);
    }

    if (lane == 0) {
        out[0] = a0;
        out[1] = a1;
        out[2] = a2;
        out[3] = a3;
    }
}

extern "C" void kernel_launch(void* const* d_in, const int* in_sizes, int n_in,
                              void* d_out, int out_size, void* d_ws, size_t ws_size,
                              hipStream_t stream) {
    const float* x = (const float*)d_in[0];   // [1,4] fp32
    const float* M = (const float*)d_in[1];   // [100,4,4] fp32
    float* out = (float*)d_out;               // [4] fp32

    big_fanout_kernel<<<1, 64, 0, stream>>>(x, M, out);
}